// Round 1
// baseline (3364.429 us; speedup 1.0000x reference)
//
#include <hip/hip_runtime.h>
#include <hip/hip_bf16.h>
#include <math.h>

#define N 8192
#define BATCH 2
#define NROWS (BATCH*N)

static __device__ __forceinline__ float fsubr(float a, float b){ return __fadd_rn(a, -b); }
static __device__ __forceinline__ unsigned okey(float f){
  unsigned u = __float_as_uint(f);
  return (u & 0x80000000u) ? ~u : (u | 0x80000000u);
}

// ---------------- aux: transpose xyz + |p|^2 (exact fp32 order x^2+y^2 then +z^2)
__global__ void aux_kernel(const float* __restrict__ xyz, float* __restrict__ xs, float* __restrict__ ys,
                           float* __restrict__ zs, float* __restrict__ sq){
  int i = blockIdx.x*256 + threadIdx.x;
  if (i < NROWS){
    float x = xyz[i*3+0], y = xyz[i*3+1], z = xyz[i*3+2];
    xs[i]=x; ys[i]=y; zs[i]=z;
    sq[i] = __fadd_rn(__fadd_rn(__fmul_rn(x,x),__fmul_rn(y,y)),__fmul_rn(z,z));
  }
}

// ---------------- far_val = max(xyz) + 1.0f
__global__ void farval_kernel(const float* __restrict__ xyz, float* __restrict__ farval){
  __shared__ float lm[4];
  float m = -1e30f;
  for (int i = threadIdx.x; i < NROWS*3; i += 256) m = fmaxf(m, xyz[i]);
  for (int off = 32; off; off >>= 1) m = fmaxf(m, __shfl_down(m, off));
  if ((threadIdx.x & 63) == 0) lm[threadIdx.x >> 6] = m;
  __syncthreads();
  if (threadIdx.x == 0){
    float r = fmaxf(fmaxf(lm[0],lm[1]), fmaxf(lm[2],lm[3]));
    farval[0] = __fadd_rn(r, 1.0f);
  }
}

// ---------------- Q = xyz @ w1[:3] + feat @ w1[3:]  (per global row, 128 cols)
__global__ __launch_bounds__(128) void q_kernel(const float* __restrict__ xyz, const float* __restrict__ feat,
                                                const float* __restrict__ w1, float* __restrict__ Q){
  __shared__ float sx[16][3];
  __shared__ float sf[16][64];
  const int t = threadIdx.x;
  const int row0 = blockIdx.x * 16;
  for (int j = t; j < 1024; j += 128) sf[j>>6][j&63] = feat[(size_t)row0*64 + j];
  if (t < 48) sx[t/3][t%3] = xyz[(size_t)row0*3 + t];
  __syncthreads();
  float acc[16];
  #pragma unroll
  for (int r = 0; r < 16; ++r) acc[r] = 0.0f;
  for (int c = 0; c < 3; ++c){
    float wv = w1[c*128 + t];
    #pragma unroll
    for (int r = 0; r < 16; ++r) acc[r] = fmaf(sx[r][c], wv, acc[r]);
  }
  for (int c = 0; c < 64; ++c){
    float wv = w1[(3+c)*128 + t];
    #pragma unroll
    for (int r = 0; r < 16; ++r) acc[r] = fmaf(sf[r][c], wv, acc[r]);
  }
  #pragma unroll
  for (int r = 0; r < 16; ++r) Q[(size_t)(row0+r)*128 + t] = acc[r];
}

// ---------------- KNN: per row, exact 65 smallest (d2, idx), drop rank0 (self), store 64 cand
__global__ __launch_bounds__(512) void knn_kernel(const float* __restrict__ xs, const float* __restrict__ ys,
                                                  const float* __restrict__ zs, const float* __restrict__ sq,
                                                  int* __restrict__ cand){
  __shared__ unsigned fk[N];
  __shared__ unsigned hist[2048];
  __shared__ unsigned long long win[1024];
  __shared__ int scal[8];
  const int t = threadIdx.x;
  const int base_row = blockIdx.x * 32;           // 512 blocks x 32 rows
  const int b = base_row >> 13;
  const int n0 = base_row & (N-1);
  const int pbase = b * N;
  float px[16], py[16], pz[16], ps[16];
  #pragma unroll
  for (int j = 0; j < 16; ++j){
    int i = t + j*512;
    px[j] = xs[pbase+i]; py[j] = ys[pbase+i]; pz[j] = zs[pbase+i]; ps[j] = sq[pbase+i];
  }
  for (int r = 0; r < 32; ++r){
    const int n = n0 + r;
    const float qx = xs[pbase+n], qy = ys[pbase+n], qz = zs[pbase+n], qs = sq[pbase+n];
    #pragma unroll
    for (int j = 0; j < 4; ++j) hist[t + j*512] = 0;
    __syncthreads();
    #pragma unroll
    for (int j = 0; j < 16; ++j){
      int i = t + j*512;
      float dot = __fadd_rn(__fadd_rn(__fmul_rn(px[j],qx), __fmul_rn(py[j],qy)), __fmul_rn(pz[j],qz));
      float d2  = __fadd_rn(__fadd_rn(qs, ps[j]), -__fmul_rn(2.0f, dot));
      unsigned u = okey(d2);
      fk[i] = u;
      atomicAdd(&hist[u >> 21], 1u);
    }
    __syncthreads();
    if (t < 64){
      unsigned s = 0;
      for (int k2 = 0; k2 < 32; ++k2) s += hist[t*32 + k2];
      unsigned p = s;
      for (int off = 1; off < 64; off <<= 1){ unsigned v = (unsigned)__shfl_up((int)p, off); if (t >= off) p += v; }
      int excl = (int)(p - s);
      if (excl < 65 && (int)p >= 65){ scal[0] = t; scal[1] = excl; }
    }
    __syncthreads();
    {
      int g = scal[0];
      if (t < 32){
        unsigned s = hist[g*32 + t];
        unsigned p = s;
        for (int off = 1; off < 32; off <<= 1){ unsigned v = (unsigned)__shfl_up((int)p, off); if (t >= off) p += v; }
        int before = scal[1] + (int)(p - s);
        if (before < 65 && scal[1] + (int)p >= 65) scal[2] = g*32 + t;
      }
    }
    if (t == 0) scal[3] = 0;
    __syncthreads();
    unsigned B1 = (unsigned)scal[2];
    unsigned limit = (B1 >= 2047u) ? 0xFFFFFFFFu : ((B1+1u) << 21);
    #pragma unroll
    for (int j = 0; j < 16; ++j){
      int i = t + j*512;
      unsigned u = fk[i];
      if (u < limit){
        int p = atomicAdd(&scal[3], 1);
        if (p < 1024) win[p] = ((unsigned long long)u << 32) | (unsigned)i;
      }
    }
    __syncthreads();
    int m = scal[3]; if (m > 1024) m = 1024;
    for (int e = t; e < m; e += 512){
      unsigned long long me = win[e];
      int rk = 0;
      for (int j2 = 0; j2 < m; ++j2) rk += (win[j2] < me) ? 1 : 0;
      if (rk >= 1 && rk < 65) cand[(size_t)(pbase + n)*64 + (rk-1)] = (int)(me & 0xFFFFFFFFull);
    }
    __syncthreads();
  }
}

// ---------------- scores + top16 + covariance/eigen curvature + feat_var  (one wave per row)
__global__ __launch_bounds__(256) void score_kernel(const float* __restrict__ xyz, const float* __restrict__ feat,
                                                    const float* __restrict__ Q, const float* __restrict__ b1,
                                                    const float* __restrict__ w2, const float* __restrict__ b2,
                                                    const int* __restrict__ cand,
                                                    float* __restrict__ curv, float* __restrict__ fv){
  __shared__ float sb1[128], sw2[128];
  __shared__ int ssel[4][16];
  __shared__ float sdx[4][16], sdy[4][16], sdz[4][16], snrm[4][16];
  const int t = threadIdx.x;
  if (t < 128) sb1[t] = b1[t]; else sw2[t-128] = w2[t-128];
  __syncthreads();
  const int w = t >> 6, lane = t & 63;
  const int row = blockIdx.x*4 + w;               // global row
  const int b = row >> 13;
  const int pbase = b * N;
  const int n = row & (N-1);
  const int ck = cand[(size_t)row*64 + lane];
  const float* Qn = Q + (size_t)row * 128;
  const float* Qc = Q + (size_t)(pbase + ck) * 128;
  float acc = 0.0f;
  for (int c = 0; c < 128; ++c){
    float pre = (Qc[c] - Qn[c]) + sb1[c];
    float g = 0.5f * pre * (1.0f + erff(pre * 0.70710678118654752440f));
    acc += g * sw2[c];
  }
  float score = acc + b2[0];
  unsigned key = okey(score);
  int rk = 0;
  for (int j = 0; j < 64; ++j){
    unsigned kj = (unsigned)__shfl((int)key, j);
    rk += (kj > key || (kj == key && j < lane)) ? 1 : 0;
  }
  float cx = xyz[(size_t)(pbase+ck)*3+0], cy = xyz[(size_t)(pbase+ck)*3+1], cz = xyz[(size_t)(pbase+ck)*3+2];
  float qxv = xyz[(size_t)(pbase+n)*3+0], qyv = xyz[(size_t)(pbase+n)*3+1], qzv = xyz[(size_t)(pbase+n)*3+2];
  if (rk < 16){
    ssel[w][rk] = ck;
    sdx[w][rk] = fsubr(cx, qxv);
    sdy[w][rk] = fsubr(cy, qyv);
    sdz[w][rk] = fsubr(cz, qzv);
  }
  __syncthreads();
  if (lane < 16){
    int si = ssel[w][lane];
    const float* fc = feat + (size_t)(pbase+si)*64;
    const float* fn = feat + (size_t)(pbase+n)*64;
    double s = 0.0;
    for (int c = 0; c < 64; ++c){
      float d = fsubr(fc[c], fn[c]);
      s += (double)d * (double)d;
    }
    snrm[w][lane] = sqrtf((float)s);
  }
  __syncthreads();
  if (lane == 0){
    double cxx=0, cxy=0, cxz=0, cyy=0, cyz=0, czz=0;
    for (int k2 = 0; k2 < 16; ++k2){
      double dx = (double)sdx[w][k2], dy = (double)sdy[w][k2], dz = (double)sdz[w][k2];
      cxx += dx*dx; cxy += dx*dy; cxz += dx*dz; cyy += dy*dy; cyz += dy*dz; czz += dz*dz;
    }
    float fxx = (float)(cxx/16.0), fxy = (float)(cxy/16.0), fxz = (float)(cxz/16.0);
    float fyy = (float)(cyy/16.0), fyz = (float)(cyz/16.0), fzz = (float)(czz/16.0);
    double a = fxx, bbv = fyy, c = fzz, d = fxy, e = fyz, f = fxz;
    double p1 = d*d + f*f + e*e;
    double e0, e1, e2v;
    if (p1 == 0.0){ e0 = a; e1 = bbv; e2v = c; }
    else {
      double q = (a + bbv + c) / 3.0;
      double aa = a - q, bq = bbv - q, cc = c - q;
      double p2 = aa*aa + bq*bq + cc*cc + 2.0*p1;
      double p = sqrt(p2 / 6.0);
      double inv = 1.0 / p;
      double bxx = aa*inv, byy = bq*inv, bzz = cc*inv, bxy = d*inv, bxz = f*inv, byz = e*inv;
      double detB = bxx*(byy*bzz - byz*byz) - bxy*(bxy*bzz - byz*bxz) + bxz*(bxy*byz - byy*bxz);
      double rr = 0.5 * detB;
      rr = fmin(1.0, fmax(-1.0, rr));
      double phi = acos(rr) / 3.0;
      e0 = q + 2.0*p*cos(phi);
      e2v = q + 2.0*p*cos(phi + 2.0943951023931953);
      e1 = 3.0*q - e0 - e2v;
    }
    double s0 = fabs(e0), s1 = fabs(e1), s2d = fabs(e2v), tt;
    if (s0 < s1){ tt=s0; s0=s1; s1=tt; }
    if (s1 < s2d){ tt=s1; s1=s2d; s2d=tt; }
    if (s0 < s1){ tt=s0; s0=s1; s1=tt; }
    float sv0 = (float)s0, sv1 = (float)s1, sv2 = (float)s2d;
    float l2f = __fmul_rn(sv0,sv0), l1f = __fmul_rn(sv1,sv1), l0f = __fmul_rn(sv2,sv2);
    float den = __fadd_rn(__fadd_rn(__fadd_rn(l0f, l1f), l2f), 1e-8f);
    curv[row] = l0f / den;
    double fs = 0.0;
    for (int k2 = 0; k2 < 16; ++k2) fs += (double)snrm[w][k2];
    fv[row] = (float)(fs / 16.0);
  }
}

// ---------------- per-batch znorm + importance
static __device__ __forceinline__ double blk_sum(double v, double* lds, int t){
  for (int off = 32; off; off >>= 1) v += __shfl_down(v, off);
  int w = t >> 6, lane = t & 63;
  if (lane == 0) lds[w] = v;
  __syncthreads();
  double r = (t < 16) ? lds[t] : 0.0;
  if (t < 64){ for (int off = 8; off; off >>= 1) r += __shfl_down(r, off); }
  if (t == 0) lds[0] = r;
  __syncthreads();
  double out = lds[0];
  __syncthreads();
  return out;
}

__global__ __launch_bounds__(1024) void stats_kernel(const float* __restrict__ curv, const float* __restrict__ fv,
                                                     float* __restrict__ imp){
  __shared__ double lds[16];
  const int t = threadIdx.x;
  const int base = blockIdx.x * N;
  double sc = 0, sf = 0;
  for (int j = 0; j < 8; ++j){ int i = t + j*1024; sc += (double)curv[base+i]; sf += (double)fv[base+i]; }
  double Sc = blk_sum(sc, lds, t);
  double Sf = blk_sum(sf, lds, t);
  double mc = Sc/8192.0, mf = Sf/8192.0;
  double vc = 0, vf = 0;
  for (int j = 0; j < 8; ++j){ int i = t + j*1024;
    double d1 = (double)curv[base+i] - mc; vc += d1*d1;
    double d2 = (double)fv[base+i]  - mf; vf += d2*d2; }
  double Vc = blk_sum(vc, lds, t);
  double Vf = blk_sum(vf, lds, t);
  float mcf = (float)mc, mff = (float)mf;
  float dc = __fadd_rn((float)sqrt(Vc/8191.0), 1e-8f);
  float df = __fadd_rn((float)sqrt(Vf/8191.0), 1e-8f);
  for (int j = 0; j < 8; ++j){ int i = t + j*1024;
    float zc = fsubr(curv[base+i], mcf) / dc;
    float zf = fsubr(fv[base+i],  mff) / df;
    imp[base+i] = __fadd_rn(zc, __fmul_rn(0.5f, zf));
  }
}

// ---------------- top-1024 importance (ordered) -> curv_idx + mask
__global__ __launch_bounds__(1024) void topk_kernel(const float* __restrict__ imp, int* __restrict__ merged,
                                                    int* __restrict__ mask){
  __shared__ unsigned dk[N];
  __shared__ unsigned hist[2048];
  __shared__ unsigned long long win[2048];
  __shared__ int scal[8];
  const int t = threadIdx.x;
  const int b = blockIdx.x;
  const int base = b * N;
  #pragma unroll
  for (int j = 0; j < 2; ++j) hist[t + j*1024] = 0;
  if (t == 0) scal[3] = 0;
  __syncthreads();
  for (int j = 0; j < 8; ++j){
    int i = t + j*1024;
    unsigned u = ~okey(imp[base+i]);   // ascending = descending importance
    dk[i] = u;
    atomicAdd(&hist[u >> 21], 1u);
  }
  __syncthreads();
  if (t < 64){
    unsigned s = 0;
    for (int k2 = 0; k2 < 32; ++k2) s += hist[t*32 + k2];
    unsigned p = s;
    for (int off = 1; off < 64; off <<= 1){ unsigned v = (unsigned)__shfl_up((int)p, off); if (t >= off) p += v; }
    int excl = (int)(p - s);
    if (excl < 1024 && (int)p >= 1024){ scal[0] = t; scal[1] = excl; }
  }
  __syncthreads();
  {
    int g = scal[0];
    if (t < 32){
      unsigned s = hist[g*32 + t];
      unsigned p = s;
      for (int off = 1; off < 32; off <<= 1){ unsigned v = (unsigned)__shfl_up((int)p, off); if (t >= off) p += v; }
      int before = scal[1] + (int)(p - s);
      if (before < 1024 && scal[1] + (int)p >= 1024) scal[2] = g*32 + t;
    }
  }
  __syncthreads();
  unsigned B1 = (unsigned)scal[2];
  unsigned limit = (B1 >= 2047u) ? 0xFFFFFFFFu : ((B1+1u) << 21);
  for (int j = 0; j < 8; ++j){
    int i = t + j*1024;
    unsigned u = dk[i];
    if (u < limit){
      int p = atomicAdd(&scal[3], 1);
      if (p < 2048) win[p] = ((unsigned long long)u << 13) | (unsigned)i;
    }
  }
  __syncthreads();
  int m = scal[3]; if (m > 2048) m = 2048;
  for (int e = t; e < m; e += 1024){
    unsigned long long me = win[e];
    int rk = 0;
    for (int j2 = 0; j2 < m; ++j2) rk += (win[j2] < me) ? 1 : 0;
    if (rk < 1024){
      int idx = (int)(me & 0x1FFFull);
      merged[b*2048 + rk] = idx;
      mask[base + idx] = 1;
    }
  }
}

// ---------------- FPS (bit-exact fp32 chain), 1 block per batch
__global__ __launch_bounds__(1024) void fps_kernel(const float* __restrict__ xs, const float* __restrict__ ys,
                                                   const float* __restrict__ zs, const int* __restrict__ mask,
                                                   const float* __restrict__ farval, int* __restrict__ merged){
  __shared__ unsigned long long wkey[16];
  __shared__ float wx[16], wy[16], wz[16];
  __shared__ float winx, winy, winz;
  const int t = threadIdx.x;
  const int b = blockIdx.x;
  const int base = b * N;
  const float far = farval[0];
  float px[8], py[8], pz[8], md[8];
  #pragma unroll
  for (int j = 0; j < 8; ++j){
    int i = t + j*1024;
    int msk = mask[base+i];
    px[j] = msk ? far : xs[base+i];
    py[j] = msk ? far : ys[base+i];
    pz[j] = msk ? far : zs[base+i];
    md[j] = 1e10f;
  }
  if (t == 0){
    winx = px[0]; winy = py[0]; winz = pz[0];
    merged[b*2048 + 1024] = 0;                       // first fps output is index 0
  }
  __syncthreads();
  const int w = t >> 6, lane = t & 63;
  for (int it = 0; it < 1024; ++it){
    float lx = winx, ly = winy, lz = winz;
    unsigned long long best = 0ull;
    float bx = 0.f, by = 0.f, bz = 0.f;
    #pragma unroll
    for (int j = 0; j < 8; ++j){
      float dx = fsubr(px[j], lx), dy = fsubr(py[j], ly), dz = fsubr(pz[j], lz);
      float d = __fadd_rn(__fadd_rn(__fmul_rn(dx,dx), __fmul_rn(dy,dy)), __fmul_rn(dz,dz));
      float nm = fminf(md[j], d);
      md[j] = nm;
      unsigned long long key = ((unsigned long long)__float_as_uint(nm) << 13)
                             | (unsigned long long)(8191 - (t + j*1024));
      if (key > best){ best = key; bx = px[j]; by = py[j]; bz = pz[j]; }
    }
    #pragma unroll
    for (int off = 32; off; off >>= 1){
      unsigned long long ok2 = __shfl_down(best, off);
      float ox = __shfl_down(bx, off), oy = __shfl_down(by, off), oz = __shfl_down(bz, off);
      if (ok2 > best){ best = ok2; bx = ox; by = oy; bz = oz; }
    }
    if (lane == 0){ wkey[w] = best; wx[w] = bx; wy[w] = by; wz[w] = bz; }
    __syncthreads();
    if (t < 64){
      unsigned long long bb = (t < 16) ? wkey[t] : 0ull;
      float cx2 = (t < 16) ? wx[t] : 0.f, cy2 = (t < 16) ? wy[t] : 0.f, cz2 = (t < 16) ? wz[t] : 0.f;
      #pragma unroll
      for (int off = 8; off; off >>= 1){
        unsigned long long ok2 = __shfl_down(bb, off);
        float ox = __shfl_down(cx2, off), oy = __shfl_down(cy2, off), oz = __shfl_down(cz2, off);
        if (ok2 > bb){ bb = ok2; cx2 = ox; cy2 = oy; cz2 = oz; }
      }
      if (t == 0){
        winx = cx2; winy = cy2; winz = cz2;
        if (it < 1023) merged[b*2048 + 1024 + it + 1] = 8191 - (int)(bb & 0x1FFFull);
      }
    }
    __syncthreads();
  }
}

// ---------------- gather outputs: coords + merged-as-float
__global__ void finalize_kernel(const float* __restrict__ xyz, const int* __restrict__ merged,
                                float* __restrict__ out){
  int i = blockIdx.x*256 + threadIdx.x;
  if (i < BATCH*2048){
    int b = i >> 11;
    int idx = merged[i];
    out[12288 + i] = (float)idx;
    const float* p = xyz + (size_t)(b*N + idx)*3;
    out[i*3+0] = p[0]; out[i*3+1] = p[1]; out[i*3+2] = p[2];
  }
}

extern "C" void kernel_launch(void* const* d_in, const int* in_sizes, int n_in,
                              void* d_out, int out_size, void* d_ws, size_t ws_size,
                              hipStream_t stream){
  const float* xyz  = (const float*)d_in[0];
  const float* feat = (const float*)d_in[1];
  const float* w1   = (const float*)d_in[2];
  const float* b1   = (const float*)d_in[3];
  const float* w2   = (const float*)d_in[4];
  const float* b2   = (const float*)d_in[5];
  float* out = (float*)d_out;
  char* ws = (char*)d_ws;
  float* Q      = (float*)(ws);                    // 16384*128 f32 = 8 MB
  int*   cand   = (int*)  (ws + 8388608);          // 16384*64  i32 = 4 MB
  float* xs     = (float*)(ws + 12582912);
  float* ysv    = (float*)(ws + 12648448);
  float* zsv    = (float*)(ws + 12713984);
  float* sq     = (float*)(ws + 12779520);
  float* curv   = (float*)(ws + 12845056);
  float* fv     = (float*)(ws + 12910592);
  float* imp    = (float*)(ws + 12976128);
  int*   mask   = (int*)  (ws + 13041664);
  int*   merged = (int*)  (ws + 13107200);
  float* farval = (float*)(ws + 13123584);

  hipMemsetAsync(mask, 0, NROWS*sizeof(int), stream);
  aux_kernel<<<64, 256, 0, stream>>>(xyz, xs, ysv, zsv, sq);
  farval_kernel<<<1, 256, 0, stream>>>(xyz, farval);
  q_kernel<<<1024, 128, 0, stream>>>(xyz, feat, w1, Q);
  knn_kernel<<<512, 512, 0, stream>>>(xs, ysv, zsv, sq, cand);
  score_kernel<<<4096, 256, 0, stream>>>(xyz, feat, Q, b1, w2, b2, cand, curv, fv);
  stats_kernel<<<2, 1024, 0, stream>>>(curv, fv, imp);
  topk_kernel<<<2, 1024, 0, stream>>>(imp, merged, mask);
  fps_kernel<<<2, 1024, 0, stream>>>(xs, ysv, zsv, mask, farval, merged);
  finalize_kernel<<<16, 256, 0, stream>>>(xyz, merged, out);
}

// Round 2
// 2401.701 us; speedup vs baseline: 1.4009x; 1.4009x over previous
//
#include <hip/hip_runtime.h>
#include <hip/hip_bf16.h>
#include <math.h>

#define N 8192
#define BATCH 2
#define NROWS (BATCH*N)

static __device__ __forceinline__ float fsubr(float a, float b){ return __fadd_rn(a, -b); }
static __device__ __forceinline__ unsigned okey(float f){
  unsigned u = __float_as_uint(f);
  return (u & 0x80000000u) ? ~u : (u | 0x80000000u);
}

// ---------------- aux: transpose xyz + |p|^2 (exact fp32 order x^2+y^2 then +z^2)
__global__ void aux_kernel(const float* __restrict__ xyz, float* __restrict__ xs, float* __restrict__ ys,
                           float* __restrict__ zs, float* __restrict__ sq){
  int i = blockIdx.x*256 + threadIdx.x;
  if (i < NROWS){
    float x = xyz[i*3+0], y = xyz[i*3+1], z = xyz[i*3+2];
    xs[i]=x; ys[i]=y; zs[i]=z;
    sq[i] = __fadd_rn(__fadd_rn(__fmul_rn(x,x),__fmul_rn(y,y)),__fmul_rn(z,z));
  }
}

// ---------------- far_val = max(xyz) + 1.0f
__global__ void farval_kernel(const float* __restrict__ xyz, float* __restrict__ farval){
  __shared__ float lm[4];
  float m = -1e30f;
  for (int i = threadIdx.x; i < NROWS*3; i += 256) m = fmaxf(m, xyz[i]);
  for (int off = 32; off; off >>= 1) m = fmaxf(m, __shfl_down(m, off));
  if ((threadIdx.x & 63) == 0) lm[threadIdx.x >> 6] = m;
  __syncthreads();
  if (threadIdx.x == 0){
    float r = fmaxf(fmaxf(lm[0],lm[1]), fmaxf(lm[2],lm[3]));
    farval[0] = __fadd_rn(r, 1.0f);
  }
}

// ---------------- Q = xyz @ w1[:3] + feat @ w1[3:]  (per global row, 128 cols)
__global__ __launch_bounds__(128) void q_kernel(const float* __restrict__ xyz, const float* __restrict__ feat,
                                                const float* __restrict__ w1, float* __restrict__ Q){
  __shared__ float sx[16][3];
  __shared__ float sf[16][64];
  const int t = threadIdx.x;
  const int row0 = blockIdx.x * 16;
  for (int j = t; j < 1024; j += 128) sf[j>>6][j&63] = feat[(size_t)row0*64 + j];
  if (t < 48) sx[t/3][t%3] = xyz[(size_t)row0*3 + t];
  __syncthreads();
  float acc[16];
  #pragma unroll
  for (int r = 0; r < 16; ++r) acc[r] = 0.0f;
  for (int c = 0; c < 3; ++c){
    float wv = w1[c*128 + t];
    #pragma unroll
    for (int r = 0; r < 16; ++r) acc[r] = fmaf(sx[r][c], wv, acc[r]);
  }
  for (int c = 0; c < 64; ++c){
    float wv = w1[(3+c)*128 + t];
    #pragma unroll
    for (int r = 0; r < 16; ++r) acc[r] = fmaf(sf[r][c], wv, acc[r]);
  }
  #pragma unroll
  for (int r = 0; r < 16; ++r) Q[(size_t)(row0+r)*128 + t] = acc[r];
}

// ---------------- KNN: per row, exact 65 smallest (d2, idx), drop rank0 (self), store 64 cand
__global__ __launch_bounds__(512) void knn_kernel(const float* __restrict__ xs, const float* __restrict__ ys,
                                                  const float* __restrict__ zs, const float* __restrict__ sq,
                                                  int* __restrict__ cand){
  __shared__ unsigned fk[N];
  __shared__ unsigned hist[2048];
  __shared__ unsigned long long win[1024];
  __shared__ int scal[8];
  const int t = threadIdx.x;
  const int base_row = blockIdx.x * 32;           // 512 blocks x 32 rows
  const int b = base_row >> 13;
  const int n0 = base_row & (N-1);
  const int pbase = b * N;
  float px[16], py[16], pz[16], ps[16];
  #pragma unroll
  for (int j = 0; j < 16; ++j){
    int i = t + j*512;
    px[j] = xs[pbase+i]; py[j] = ys[pbase+i]; pz[j] = zs[pbase+i]; ps[j] = sq[pbase+i];
  }
  for (int r = 0; r < 32; ++r){
    const int n = n0 + r;
    const float qx = xs[pbase+n], qy = ys[pbase+n], qz = zs[pbase+n], qs = sq[pbase+n];
    #pragma unroll
    for (int j = 0; j < 4; ++j) hist[t + j*512] = 0;
    __syncthreads();
    #pragma unroll
    for (int j = 0; j < 16; ++j){
      int i = t + j*512;
      float dot = __fadd_rn(__fadd_rn(__fmul_rn(px[j],qx), __fmul_rn(py[j],qy)), __fmul_rn(pz[j],qz));
      float d2  = __fadd_rn(__fadd_rn(qs, ps[j]), -__fmul_rn(2.0f, dot));
      unsigned u = okey(d2);
      fk[i] = u;
      atomicAdd(&hist[u >> 21], 1u);
    }
    __syncthreads();
    if (t < 64){
      unsigned s = 0;
      for (int k2 = 0; k2 < 32; ++k2) s += hist[t*32 + k2];
      unsigned p = s;
      for (int off = 1; off < 64; off <<= 1){ unsigned v = (unsigned)__shfl_up((int)p, off); if (t >= off) p += v; }
      int excl = (int)(p - s);
      if (excl < 65 && (int)p >= 65){ scal[0] = t; scal[1] = excl; }
    }
    __syncthreads();
    {
      int g = scal[0];
      if (t < 32){
        unsigned s = hist[g*32 + t];
        unsigned p = s;
        for (int off = 1; off < 32; off <<= 1){ unsigned v = (unsigned)__shfl_up((int)p, off); if (t >= off) p += v; }
        int before = scal[1] + (int)(p - s);
        if (before < 65 && scal[1] + (int)p >= 65) scal[2] = g*32 + t;
      }
    }
    if (t == 0) scal[3] = 0;
    __syncthreads();
    unsigned B1 = (unsigned)scal[2];
    unsigned limit = (B1 >= 2047u) ? 0xFFFFFFFFu : ((B1+1u) << 21);
    #pragma unroll
    for (int j = 0; j < 16; ++j){
      int i = t + j*512;
      unsigned u = fk[i];
      if (u < limit){
        int p = atomicAdd(&scal[3], 1);
        if (p < 1024) win[p] = ((unsigned long long)u << 32) | (unsigned)i;
      }
    }
    __syncthreads();
    int m = scal[3]; if (m > 1024) m = 1024;
    for (int e = t; e < m; e += 512){
      unsigned long long me = win[e];
      int rk = 0;
      for (int j2 = 0; j2 < m; ++j2) rk += (win[j2] < me) ? 1 : 0;
      if (rk >= 1 && rk < 65) cand[(size_t)(pbase + n)*64 + (rk-1)] = (int)(me & 0xFFFFFFFFull);
    }
    __syncthreads();
  }
}

// ---------------- scores + top16 + covariance/eigen curvature + feat_var  (one wave per row)
__global__ __launch_bounds__(256) void score_kernel(const float* __restrict__ xyz, const float* __restrict__ feat,
                                                    const float* __restrict__ Q, const float* __restrict__ b1,
                                                    const float* __restrict__ w2, const float* __restrict__ b2,
                                                    const int* __restrict__ cand,
                                                    float* __restrict__ curv, float* __restrict__ fv){
  __shared__ float sb1[128], sw2[128];
  __shared__ int ssel[4][16];
  __shared__ float sdx[4][16], sdy[4][16], sdz[4][16], snrm[4][16];
  const int t = threadIdx.x;
  if (t < 128) sb1[t] = b1[t]; else sw2[t-128] = w2[t-128];
  __syncthreads();
  const int w = t >> 6, lane = t & 63;
  const int row = blockIdx.x*4 + w;               // global row
  const int b = row >> 13;
  const int pbase = b * N;
  const int n = row & (N-1);
  const int ck = cand[(size_t)row*64 + lane];
  const float* Qn = Q + (size_t)row * 128;
  const float* Qc = Q + (size_t)(pbase + ck) * 128;
  float acc = 0.0f;
  for (int c = 0; c < 128; ++c){
    float pre = (Qc[c] - Qn[c]) + sb1[c];
    float g = 0.5f * pre * (1.0f + erff(pre * 0.70710678118654752440f));
    acc += g * sw2[c];
  }
  float score = acc + b2[0];
  unsigned key = okey(score);
  int rk = 0;
  for (int j = 0; j < 64; ++j){
    unsigned kj = (unsigned)__shfl((int)key, j);
    rk += (kj > key || (kj == key && j < lane)) ? 1 : 0;
  }
  float cx = xyz[(size_t)(pbase+ck)*3+0], cy = xyz[(size_t)(pbase+ck)*3+1], cz = xyz[(size_t)(pbase+ck)*3+2];
  float qxv = xyz[(size_t)(pbase+n)*3+0], qyv = xyz[(size_t)(pbase+n)*3+1], qzv = xyz[(size_t)(pbase+n)*3+2];
  if (rk < 16){
    ssel[w][rk] = ck;
    sdx[w][rk] = fsubr(cx, qxv);
    sdy[w][rk] = fsubr(cy, qyv);
    sdz[w][rk] = fsubr(cz, qzv);
  }
  __syncthreads();
  if (lane < 16){
    int si = ssel[w][lane];
    const float* fc = feat + (size_t)(pbase+si)*64;
    const float* fn = feat + (size_t)(pbase+n)*64;
    double s = 0.0;
    for (int c = 0; c < 64; ++c){
      float d = fsubr(fc[c], fn[c]);
      s += (double)d * (double)d;
    }
    snrm[w][lane] = sqrtf((float)s);
  }
  __syncthreads();
  if (lane == 0){
    double cxx=0, cxy=0, cxz=0, cyy=0, cyz=0, czz=0;
    for (int k2 = 0; k2 < 16; ++k2){
      double dx = (double)sdx[w][k2], dy = (double)sdy[w][k2], dz = (double)sdz[w][k2];
      cxx += dx*dx; cxy += dx*dy; cxz += dx*dz; cyy += dy*dy; cyz += dy*dz; czz += dz*dz;
    }
    float fxx = (float)(cxx/16.0), fxy = (float)(cxy/16.0), fxz = (float)(cxz/16.0);
    float fyy = (float)(cyy/16.0), fyz = (float)(cyz/16.0), fzz = (float)(czz/16.0);
    double a = fxx, bbv = fyy, c = fzz, d = fxy, e = fyz, f = fxz;
    double p1 = d*d + f*f + e*e;
    double e0, e1, e2v;
    if (p1 == 0.0){ e0 = a; e1 = bbv; e2v = c; }
    else {
      double q = (a + bbv + c) / 3.0;
      double aa = a - q, bq = bbv - q, cc = c - q;
      double p2 = aa*aa + bq*bq + cc*cc + 2.0*p1;
      double p = sqrt(p2 / 6.0);
      double inv = 1.0 / p;
      double bxx = aa*inv, byy = bq*inv, bzz = cc*inv, bxy = d*inv, bxz = f*inv, byz = e*inv;
      double detB = bxx*(byy*bzz - byz*byz) - bxy*(bxy*bzz - byz*bxz) + bxz*(bxy*byz - byy*bxz);
      double rr = 0.5 * detB;
      rr = fmin(1.0, fmax(-1.0, rr));
      double phi = acos(rr) / 3.0;
      e0 = q + 2.0*p*cos(phi);
      e2v = q + 2.0*p*cos(phi + 2.0943951023931953);
      e1 = 3.0*q - e0 - e2v;
    }
    double s0 = fabs(e0), s1 = fabs(e1), s2d = fabs(e2v), tt;
    if (s0 < s1){ tt=s0; s0=s1; s1=tt; }
    if (s1 < s2d){ tt=s1; s1=s2d; s2d=tt; }
    if (s0 < s1){ tt=s0; s0=s1; s1=tt; }
    float sv0 = (float)s0, sv1 = (float)s1, sv2 = (float)s2d;
    float l2f = __fmul_rn(sv0,sv0), l1f = __fmul_rn(sv1,sv1), l0f = __fmul_rn(sv2,sv2);
    float den = __fadd_rn(__fadd_rn(__fadd_rn(l0f, l1f), l2f), 1e-8f);
    curv[row] = l0f / den;
    double fs = 0.0;
    for (int k2 = 0; k2 < 16; ++k2) fs += (double)snrm[w][k2];
    fv[row] = (float)(fs / 16.0);
  }
}

// ---------------- per-batch znorm + importance
static __device__ __forceinline__ double blk_sum(double v, double* lds, int t){
  for (int off = 32; off; off >>= 1) v += __shfl_down(v, off);
  int w = t >> 6, lane = t & 63;
  if (lane == 0) lds[w] = v;
  __syncthreads();
  double r = (t < 16) ? lds[t] : 0.0;
  if (t < 64){ for (int off = 8; off; off >>= 1) r += __shfl_down(r, off); }
  if (t == 0) lds[0] = r;
  __syncthreads();
  double out = lds[0];
  __syncthreads();
  return out;
}

__global__ __launch_bounds__(1024) void stats_kernel(const float* __restrict__ curv, const float* __restrict__ fv,
                                                     float* __restrict__ imp){
  __shared__ double lds[16];
  const int t = threadIdx.x;
  const int base = blockIdx.x * N;
  double sc = 0, sf = 0;
  for (int j = 0; j < 8; ++j){ int i = t + j*1024; sc += (double)curv[base+i]; sf += (double)fv[base+i]; }
  double Sc = blk_sum(sc, lds, t);
  double Sf = blk_sum(sf, lds, t);
  double mc = Sc/8192.0, mf = Sf/8192.0;
  double vc = 0, vf = 0;
  for (int j = 0; j < 8; ++j){ int i = t + j*1024;
    double d1 = (double)curv[base+i] - mc; vc += d1*d1;
    double d2 = (double)fv[base+i]  - mf; vf += d2*d2; }
  double Vc = blk_sum(vc, lds, t);
  double Vf = blk_sum(vf, lds, t);
  float mcf = (float)mc, mff = (float)mf;
  float dc = __fadd_rn((float)sqrt(Vc/8191.0), 1e-8f);
  float df = __fadd_rn((float)sqrt(Vf/8191.0), 1e-8f);
  for (int j = 0; j < 8; ++j){ int i = t + j*1024;
    float zc = fsubr(curv[base+i], mcf) / dc;
    float zf = fsubr(fv[base+i],  mff) / df;
    imp[base+i] = __fadd_rn(zc, __fmul_rn(0.5f, zf));
  }
}

// ---------------- top-1024 importance (ordered) -> curv_idx + mask
__global__ __launch_bounds__(1024) void topk_kernel(const float* __restrict__ imp, int* __restrict__ merged,
                                                    int* __restrict__ mask){
  __shared__ unsigned dk[N];
  __shared__ unsigned hist[2048];
  __shared__ unsigned long long win[2048];
  __shared__ int scal[8];
  const int t = threadIdx.x;
  const int b = blockIdx.x;
  const int base = b * N;
  #pragma unroll
  for (int j = 0; j < 2; ++j) hist[t + j*1024] = 0;
  if (t == 0) scal[3] = 0;
  __syncthreads();
  for (int j = 0; j < 8; ++j){
    int i = t + j*1024;
    unsigned u = ~okey(imp[base+i]);   // ascending = descending importance
    dk[i] = u;
    atomicAdd(&hist[u >> 21], 1u);
  }
  __syncthreads();
  if (t < 64){
    unsigned s = 0;
    for (int k2 = 0; k2 < 32; ++k2) s += hist[t*32 + k2];
    unsigned p = s;
    for (int off = 1; off < 64; off <<= 1){ unsigned v = (unsigned)__shfl_up((int)p, off); if (t >= off) p += v; }
    int excl = (int)(p - s);
    if (excl < 1024 && (int)p >= 1024){ scal[0] = t; scal[1] = excl; }
  }
  __syncthreads();
  {
    int g = scal[0];
    if (t < 32){
      unsigned s = hist[g*32 + t];
      unsigned p = s;
      for (int off = 1; off < 32; off <<= 1){ unsigned v = (unsigned)__shfl_up((int)p, off); if (t >= off) p += v; }
      int before = scal[1] + (int)(p - s);
      if (before < 1024 && scal[1] + (int)p >= 1024) scal[2] = g*32 + t;
    }
  }
  __syncthreads();
  unsigned B1 = (unsigned)scal[2];
  unsigned limit = (B1 >= 2047u) ? 0xFFFFFFFFu : ((B1+1u) << 21);
  for (int j = 0; j < 8; ++j){
    int i = t + j*1024;
    unsigned u = dk[i];
    if (u < limit){
      int p = atomicAdd(&scal[3], 1);
      if (p < 2048) win[p] = ((unsigned long long)u << 13) | (unsigned)i;
    }
  }
  __syncthreads();
  int m = scal[3]; if (m > 2048) m = 2048;
  for (int e = t; e < m; e += 1024){
    unsigned long long me = win[e];
    int rk = 0;
    for (int j2 = 0; j2 < m; ++j2) rk += (win[j2] < me) ? 1 : 0;
    if (rk < 1024){
      int idx = (int)(me & 0x1FFFull);
      merged[b*2048 + rk] = idx;
      mask[base + idx] = 1;
    }
  }
}

// ---------------- FPS (bit-exact fp32 chain), 1 block per batch
// R1 redesign: 512 thr x 16 pts; per-thread f32 best w/ coord cndmask tracking;
// key-only 64-bit wave reduce (12 bpermutes/wave vs 30); one ds_atomic_max_u64
// per wave into 2-slot round-robin; unique winner thread pushes coords.
__global__ __launch_bounds__(512) void fps_kernel(const float* __restrict__ xs, const float* __restrict__ ys,
                                                  const float* __restrict__ zs, const int* __restrict__ mask,
                                                  const float* __restrict__ farval, int* __restrict__ merged){
  __shared__ unsigned long long slotK[2];
  __shared__ float wxyz[3];
  const int t = threadIdx.x;
  const int b = blockIdx.x;
  const int base = b * N;
  const float far = farval[0];
  float px[16], py[16], pz[16], md[16];
  #pragma unroll
  for (int j = 0; j < 16; ++j){
    int i = t + j*512;
    int msk = mask[base+i];
    px[j] = msk ? far : xs[base+i];
    py[j] = msk ? far : ys[base+i];
    pz[j] = msk ? far : zs[base+i];
    md[j] = 1e10f;
  }
  if (t == 0){
    merged[b*2048 + 1024] = 0;                 // first fps output is index 0
    wxyz[0] = px[0]; wxyz[1] = py[0]; wxyz[2] = pz[0];   // t0 owns point 0 (j=0)
    slotK[0] = 0ull; slotK[1] = 0ull;
  }
  __syncthreads();
  for (int it = 0; it < 1024; ++it){
    const float lx = wxyz[0], ly = wxyz[1], lz = wxyz[2];
    float bestv = -1.0f, bx = 0.f, by = 0.f, bz = 0.f;
    int bidx = 0;
    #pragma unroll
    for (int j = 0; j < 16; ++j){
      float dx = fsubr(px[j], lx), dy = fsubr(py[j], ly), dz = fsubr(pz[j], lz);
      float d = __fadd_rn(__fadd_rn(__fmul_rn(dx,dx), __fmul_rn(dy,dy)), __fmul_rn(dz,dz));
      float nm = fminf(md[j], d);
      md[j] = nm;
      if (nm > bestv){ bestv = nm; bidx = t + (j<<9); bx = px[j]; by = py[j]; bz = pz[j]; }
    }
    const unsigned long long mykey = ((unsigned long long)__float_as_uint(bestv) << 13)
                                   | (unsigned long long)(8191 - bidx);
    unsigned long long key = mykey;
    #pragma unroll
    for (int off = 32; off; off >>= 1){
      unsigned long long o = __shfl_down(key, off);
      if (o > key) key = o;
    }
    const int s = it & 1;
    if ((t & 63) == 0) atomicMax(&slotK[s], key);
    __syncthreads();
    const unsigned long long k = slotK[s];
    if (mykey == k){                            // unique owner (idx field unique)
      wxyz[0] = bx; wxyz[1] = by; wxyz[2] = bz;
    }
    if (t == 0){
      slotK[1-s] = 0ull;                        // safe: last read before prev barrier pair
      if (it < 1023) merged[b*2048 + 1024 + it + 1] = 8191 - (int)(k & 0x1FFFull);
    }
    __syncthreads();
  }
}

// ---------------- gather outputs: coords + merged-as-float
__global__ void finalize_kernel(const float* __restrict__ xyz, const int* __restrict__ merged,
                                float* __restrict__ out){
  int i = blockIdx.x*256 + threadIdx.x;
  if (i < BATCH*2048){
    int b = i >> 11;
    int idx = merged[i];
    out[12288 + i] = (float)idx;
    const float* p = xyz + (size_t)(b*N + idx)*3;
    out[i*3+0] = p[0]; out[i*3+1] = p[1]; out[i*3+2] = p[2];
  }
}

extern "C" void kernel_launch(void* const* d_in, const int* in_sizes, int n_in,
                              void* d_out, int out_size, void* d_ws, size_t ws_size,
                              hipStream_t stream){
  const float* xyz  = (const float*)d_in[0];
  const float* feat = (const float*)d_in[1];
  const float* w1   = (const float*)d_in[2];
  const float* b1   = (const float*)d_in[3];
  const float* w2   = (const float*)d_in[4];
  const float* b2   = (const float*)d_in[5];
  float* out = (float*)d_out;
  char* ws = (char*)d_ws;
  float* Q      = (float*)(ws);                    // 16384*128 f32 = 8 MB
  int*   cand   = (int*)  (ws + 8388608);          // 16384*64  i32 = 4 MB
  float* xs     = (float*)(ws + 12582912);
  float* ysv    = (float*)(ws + 12648448);
  float* zsv    = (float*)(ws + 12713984);
  float* sq     = (float*)(ws + 12779520);
  float* curv   = (float*)(ws + 12845056);
  float* fv     = (float*)(ws + 12910592);
  float* imp    = (float*)(ws + 12976128);
  int*   mask   = (int*)  (ws + 13041664);
  int*   merged = (int*)  (ws + 13107200);
  float* farval = (float*)(ws + 13123584);

  hipMemsetAsync(mask, 0, NROWS*sizeof(int), stream);
  aux_kernel<<<64, 256, 0, stream>>>(xyz, xs, ysv, zsv, sq);
  farval_kernel<<<1, 256, 0, stream>>>(xyz, farval);
  q_kernel<<<1024, 128, 0, stream>>>(xyz, feat, w1, Q);
  knn_kernel<<<512, 512, 0, stream>>>(xs, ysv, zsv, sq, cand);
  score_kernel<<<4096, 256, 0, stream>>>(xyz, feat, Q, b1, w2, b2, cand, curv, fv);
  stats_kernel<<<2, 1024, 0, stream>>>(curv, fv, imp);
  topk_kernel<<<2, 1024, 0, stream>>>(imp, merged, mask);
  fps_kernel<<<2, 512, 0, stream>>>(xs, ysv, zsv, mask, farval, merged);
  finalize_kernel<<<16, 256, 0, stream>>>(xyz, merged, out);
}

// Round 3
// 2019.322 us; speedup vs baseline: 1.6661x; 1.1894x over previous
//
#include <hip/hip_runtime.h>
#include <hip/hip_bf16.h>
#include <math.h>

#define N 8192
#define BATCH 2
#define NROWS (BATCH*N)

static __device__ __forceinline__ float fsubr(float a, float b){ return __fadd_rn(a, -b); }
static __device__ __forceinline__ unsigned okey(float f){
  unsigned u = __float_as_uint(f);
  return (u & 0x80000000u) ? ~u : (u | 0x80000000u);
}

// ---------------- aux: transpose xyz + |p|^2 + masked-coord float4 image (pre-mask copy)
__global__ void aux_kernel(const float* __restrict__ xyz, float* __restrict__ xs, float* __restrict__ ys,
                           float* __restrict__ zs, float* __restrict__ sq, float4* __restrict__ mxyz){
  int i = blockIdx.x*256 + threadIdx.x;
  if (i < NROWS){
    float x = xyz[i*3+0], y = xyz[i*3+1], z = xyz[i*3+2];
    xs[i]=x; ys[i]=y; zs[i]=z;
    sq[i] = __fadd_rn(__fadd_rn(__fmul_rn(x,x),__fmul_rn(y,y)),__fmul_rn(z,z));
    mxyz[i] = make_float4(x, y, z, 0.0f);
  }
}

// ---------------- far_val = max(xyz) + 1.0f
__global__ void farval_kernel(const float* __restrict__ xyz, float* __restrict__ farval){
  __shared__ float lm[4];
  float m = -1e30f;
  for (int i = threadIdx.x; i < NROWS*3; i += 256) m = fmaxf(m, xyz[i]);
  for (int off = 32; off; off >>= 1) m = fmaxf(m, __shfl_down(m, off));
  if ((threadIdx.x & 63) == 0) lm[threadIdx.x >> 6] = m;
  __syncthreads();
  if (threadIdx.x == 0){
    float r = fmaxf(fmaxf(lm[0],lm[1]), fmaxf(lm[2],lm[3]));
    farval[0] = __fadd_rn(r, 1.0f);
  }
}

// ---------------- Q = xyz @ w1[:3] + feat @ w1[3:]  (per global row, 128 cols)
__global__ __launch_bounds__(128) void q_kernel(const float* __restrict__ xyz, const float* __restrict__ feat,
                                                const float* __restrict__ w1, float* __restrict__ Q){
  __shared__ float sx[16][3];
  __shared__ float sf[16][64];
  const int t = threadIdx.x;
  const int row0 = blockIdx.x * 16;
  for (int j = t; j < 1024; j += 128) sf[j>>6][j&63] = feat[(size_t)row0*64 + j];
  if (t < 48) sx[t/3][t%3] = xyz[(size_t)row0*3 + t];
  __syncthreads();
  float acc[16];
  #pragma unroll
  for (int r = 0; r < 16; ++r) acc[r] = 0.0f;
  for (int c = 0; c < 3; ++c){
    float wv = w1[c*128 + t];
    #pragma unroll
    for (int r = 0; r < 16; ++r) acc[r] = fmaf(sx[r][c], wv, acc[r]);
  }
  for (int c = 0; c < 64; ++c){
    float wv = w1[(3+c)*128 + t];
    #pragma unroll
    for (int r = 0; r < 16; ++r) acc[r] = fmaf(sf[r][c], wv, acc[r]);
  }
  #pragma unroll
  for (int r = 0; r < 16; ++r) Q[(size_t)(row0+r)*128 + t] = acc[r];
}

// ---------------- KNN: per row, exact 65 smallest (d2, idx), drop rank0 (self), store 64 cand
__global__ __launch_bounds__(512) void knn_kernel(const float* __restrict__ xs, const float* __restrict__ ys,
                                                  const float* __restrict__ zs, const float* __restrict__ sq,
                                                  int* __restrict__ cand){
  __shared__ unsigned fk[N];
  __shared__ unsigned hist[2048];
  __shared__ unsigned long long win[1024];
  __shared__ int scal[8];
  const int t = threadIdx.x;
  const int base_row = blockIdx.x * 32;           // 512 blocks x 32 rows
  const int b = base_row >> 13;
  const int n0 = base_row & (N-1);
  const int pbase = b * N;
  float px[16], py[16], pz[16], ps[16];
  #pragma unroll
  for (int j = 0; j < 16; ++j){
    int i = t + j*512;
    px[j] = xs[pbase+i]; py[j] = ys[pbase+i]; pz[j] = zs[pbase+i]; ps[j] = sq[pbase+i];
  }
  for (int r = 0; r < 32; ++r){
    const int n = n0 + r;
    const float qx = xs[pbase+n], qy = ys[pbase+n], qz = zs[pbase+n], qs = sq[pbase+n];
    #pragma unroll
    for (int j = 0; j < 4; ++j) hist[t + j*512] = 0;
    __syncthreads();
    #pragma unroll
    for (int j = 0; j < 16; ++j){
      int i = t + j*512;
      float dot = __fadd_rn(__fadd_rn(__fmul_rn(px[j],qx), __fmul_rn(py[j],qy)), __fmul_rn(pz[j],qz));
      float d2  = __fadd_rn(__fadd_rn(qs, ps[j]), -__fmul_rn(2.0f, dot));
      unsigned u = okey(d2);
      fk[i] = u;
      atomicAdd(&hist[u >> 21], 1u);
    }
    __syncthreads();
    if (t < 64){
      unsigned s = 0;
      for (int k2 = 0; k2 < 32; ++k2) s += hist[t*32 + k2];
      unsigned p = s;
      for (int off = 1; off < 64; off <<= 1){ unsigned v = (unsigned)__shfl_up((int)p, off); if (t >= off) p += v; }
      int excl = (int)(p - s);
      if (excl < 65 && (int)p >= 65){ scal[0] = t; scal[1] = excl; }
    }
    __syncthreads();
    {
      int g = scal[0];
      if (t < 32){
        unsigned s = hist[g*32 + t];
        unsigned p = s;
        for (int off = 1; off < 32; off <<= 1){ unsigned v = (unsigned)__shfl_up((int)p, off); if (t >= off) p += v; }
        int before = scal[1] + (int)(p - s);
        if (before < 65 && scal[1] + (int)p >= 65) scal[2] = g*32 + t;
      }
    }
    if (t == 0) scal[3] = 0;
    __syncthreads();
    unsigned B1 = (unsigned)scal[2];
    unsigned limit = (B1 >= 2047u) ? 0xFFFFFFFFu : ((B1+1u) << 21);
    #pragma unroll
    for (int j = 0; j < 16; ++j){
      int i = t + j*512;
      unsigned u = fk[i];
      if (u < limit){
        int p = atomicAdd(&scal[3], 1);
        if (p < 1024) win[p] = ((unsigned long long)u << 32) | (unsigned)i;
      }
    }
    __syncthreads();
    int m = scal[3]; if (m > 1024) m = 1024;
    for (int e = t; e < m; e += 512){
      unsigned long long me = win[e];
      int rk = 0;
      for (int j2 = 0; j2 < m; ++j2) rk += (win[j2] < me) ? 1 : 0;
      if (rk >= 1 && rk < 65) cand[(size_t)(pbase + n)*64 + (rk-1)] = (int)(me & 0xFFFFFFFFull);
    }
    __syncthreads();
  }
}

// ---------------- scores + top16 + covariance/eigen curvature + feat_var  (one wave per row)
// R3: float4 gather for Qc/Qn/b1/w2/feat (4x fewer VMEM line-touch instrs); identical fp32 op order.
__global__ __launch_bounds__(256) void score_kernel(const float* __restrict__ xyz, const float* __restrict__ feat,
                                                    const float* __restrict__ Q, const float* __restrict__ b1,
                                                    const float* __restrict__ w2, const float* __restrict__ b2,
                                                    const int* __restrict__ cand,
                                                    float* __restrict__ curv, float* __restrict__ fv){
  __shared__ float4 sb14[32], sw24[32];
  __shared__ int ssel[4][16];
  __shared__ float sdx[4][16], sdy[4][16], sdz[4][16], snrm[4][16];
  const int t = threadIdx.x;
  if (t < 32) sb14[t] = ((const float4*)b1)[t];
  else if (t < 64) sw24[t-32] = ((const float4*)w2)[t-32];
  __syncthreads();
  const int w = t >> 6, lane = t & 63;
  const int row = blockIdx.x*4 + w;               // global row
  const int b = row >> 13;
  const int pbase = b * N;
  const int n = row & (N-1);
  const int ck = cand[(size_t)row*64 + lane];
  const float4* Qn4 = (const float4*)(Q + (size_t)row * 128);
  const float4* Qc4 = (const float4*)(Q + (size_t)(pbase + ck) * 128);
  const float ks = 0.70710678118654752440f;
  float acc = 0.0f;
  for (int c = 0; c < 32; ++c){
    float4 qc = Qc4[c], qn = Qn4[c], bb = sb14[c], ww = sw24[c];
    float p0 = (qc.x - qn.x) + bb.x;
    float g0 = 0.5f * p0 * (1.0f + erff(p0 * ks));
    acc += g0 * ww.x;
    float p1 = (qc.y - qn.y) + bb.y;
    float g1 = 0.5f * p1 * (1.0f + erff(p1 * ks));
    acc += g1 * ww.y;
    float p2 = (qc.z - qn.z) + bb.z;
    float g2 = 0.5f * p2 * (1.0f + erff(p2 * ks));
    acc += g2 * ww.z;
    float p3 = (qc.w - qn.w) + bb.w;
    float g3 = 0.5f * p3 * (1.0f + erff(p3 * ks));
    acc += g3 * ww.w;
  }
  float score = acc + b2[0];
  unsigned key = okey(score);
  int rk = 0;
  for (int j = 0; j < 64; ++j){
    unsigned kj = (unsigned)__shfl((int)key, j);
    rk += (kj > key || (kj == key && j < lane)) ? 1 : 0;
  }
  float cx = xyz[(size_t)(pbase+ck)*3+0], cy = xyz[(size_t)(pbase+ck)*3+1], cz = xyz[(size_t)(pbase+ck)*3+2];
  float qxv = xyz[(size_t)(pbase+n)*3+0], qyv = xyz[(size_t)(pbase+n)*3+1], qzv = xyz[(size_t)(pbase+n)*3+2];
  if (rk < 16){
    ssel[w][rk] = ck;
    sdx[w][rk] = fsubr(cx, qxv);
    sdy[w][rk] = fsubr(cy, qyv);
    sdz[w][rk] = fsubr(cz, qzv);
  }
  __syncthreads();
  if (lane < 16){
    int si = ssel[w][lane];
    const float4* fc4 = (const float4*)(feat + (size_t)(pbase+si)*64);
    const float4* fn4 = (const float4*)(feat + (size_t)(pbase+n)*64);
    double s = 0.0;
    for (int c = 0; c < 16; ++c){
      float4 a = fc4[c], bq = fn4[c];
      float d0 = fsubr(a.x, bq.x); s += (double)d0 * (double)d0;
      float d1 = fsubr(a.y, bq.y); s += (double)d1 * (double)d1;
      float d2 = fsubr(a.z, bq.z); s += (double)d2 * (double)d2;
      float d3 = fsubr(a.w, bq.w); s += (double)d3 * (double)d3;
    }
    snrm[w][lane] = sqrtf((float)s);
  }
  __syncthreads();
  if (lane == 0){
    double cxx=0, cxy=0, cxz=0, cyy=0, cyz=0, czz=0;
    for (int k2 = 0; k2 < 16; ++k2){
      double dx = (double)sdx[w][k2], dy = (double)sdy[w][k2], dz = (double)sdz[w][k2];
      cxx += dx*dx; cxy += dx*dy; cxz += dx*dz; cyy += dy*dy; cyz += dy*dz; czz += dz*dz;
    }
    float fxx = (float)(cxx/16.0), fxy = (float)(cxy/16.0), fxz = (float)(cxz/16.0);
    float fyy = (float)(cyy/16.0), fyz = (float)(cyz/16.0), fzz = (float)(czz/16.0);
    double a = fxx, bbv = fyy, c = fzz, d = fxy, e = fyz, f = fxz;
    double p1 = d*d + f*f + e*e;
    double e0, e1, e2v;
    if (p1 == 0.0){ e0 = a; e1 = bbv; e2v = c; }
    else {
      double q = (a + bbv + c) / 3.0;
      double aa = a - q, bq = bbv - q, cc = c - q;
      double p2 = aa*aa + bq*bq + cc*cc + 2.0*p1;
      double p = sqrt(p2 / 6.0);
      double inv = 1.0 / p;
      double bxx = aa*inv, byy = bq*inv, bzz = cc*inv, bxy = d*inv, bxz = f*inv, byz = e*inv;
      double detB = bxx*(byy*bzz - byz*byz) - bxy*(bxy*bzz - byz*bxz) + bxz*(bxy*byz - byy*bxz);
      double rr = 0.5 * detB;
      rr = fmin(1.0, fmax(-1.0, rr));
      double phi = acos(rr) / 3.0;
      e0 = q + 2.0*p*cos(phi);
      e2v = q + 2.0*p*cos(phi + 2.0943951023931953);
      e1 = 3.0*q - e0 - e2v;
    }
    double s0 = fabs(e0), s1 = fabs(e1), s2d = fabs(e2v), tt;
    if (s0 < s1){ tt=s0; s0=s1; s1=tt; }
    if (s1 < s2d){ tt=s1; s1=s2d; s2d=tt; }
    if (s0 < s1){ tt=s0; s0=s1; s1=tt; }
    float sv0 = (float)s0, sv1 = (float)s1, sv2 = (float)s2d;
    float l2f = __fmul_rn(sv0,sv0), l1f = __fmul_rn(sv1,sv1), l0f = __fmul_rn(sv2,sv2);
    float den = __fadd_rn(__fadd_rn(__fadd_rn(l0f, l1f), l2f), 1e-8f);
    curv[row] = l0f / den;
    double fs = 0.0;
    for (int k2 = 0; k2 < 16; ++k2) fs += (double)snrm[w][k2];
    fv[row] = (float)(fs / 16.0);
  }
}

// ---------------- per-batch znorm + importance
static __device__ __forceinline__ double blk_sum(double v, double* lds, int t){
  for (int off = 32; off; off >>= 1) v += __shfl_down(v, off);
  int w = t >> 6, lane = t & 63;
  if (lane == 0) lds[w] = v;
  __syncthreads();
  double r = (t < 16) ? lds[t] : 0.0;
  if (t < 64){ for (int off = 8; off; off >>= 1) r += __shfl_down(r, off); }
  if (t == 0) lds[0] = r;
  __syncthreads();
  double out = lds[0];
  __syncthreads();
  return out;
}

__global__ __launch_bounds__(1024) void stats_kernel(const float* __restrict__ curv, const float* __restrict__ fv,
                                                     float* __restrict__ imp){
  __shared__ double lds[16];
  const int t = threadIdx.x;
  const int base = blockIdx.x * N;
  double sc = 0, sf = 0;
  for (int j = 0; j < 8; ++j){ int i = t + j*1024; sc += (double)curv[base+i]; sf += (double)fv[base+i]; }
  double Sc = blk_sum(sc, lds, t);
  double Sf = blk_sum(sf, lds, t);
  double mc = Sc/8192.0, mf = Sf/8192.0;
  double vc = 0, vf = 0;
  for (int j = 0; j < 8; ++j){ int i = t + j*1024;
    double d1 = (double)curv[base+i] - mc; vc += d1*d1;
    double d2 = (double)fv[base+i]  - mf; vf += d2*d2; }
  double Vc = blk_sum(vc, lds, t);
  double Vf = blk_sum(vf, lds, t);
  float mcf = (float)mc, mff = (float)mf;
  float dc = __fadd_rn((float)sqrt(Vc/8191.0), 1e-8f);
  float df = __fadd_rn((float)sqrt(Vf/8191.0), 1e-8f);
  for (int j = 0; j < 8; ++j){ int i = t + j*1024;
    float zc = fsubr(curv[base+i], mcf) / dc;
    float zf = fsubr(fv[base+i],  mff) / df;
    imp[base+i] = __fadd_rn(zc, __fmul_rn(0.5f, zf));
  }
}

// ---------------- top-1024 importance (ordered) -> curv_idx + masked-coord scatter (far)
__global__ __launch_bounds__(1024) void topk_kernel(const float* __restrict__ imp, int* __restrict__ merged,
                                                    float4* __restrict__ mxyz, const float* __restrict__ farval){
  __shared__ unsigned dk[N];
  __shared__ unsigned hist[2048];
  __shared__ unsigned long long win[2048];
  __shared__ int scal[8];
  const int t = threadIdx.x;
  const int b = blockIdx.x;
  const int base = b * N;
  #pragma unroll
  for (int j = 0; j < 2; ++j) hist[t + j*1024] = 0;
  if (t == 0) scal[3] = 0;
  __syncthreads();
  for (int j = 0; j < 8; ++j){
    int i = t + j*1024;
    unsigned u = ~okey(imp[base+i]);   // ascending = descending importance
    dk[i] = u;
    atomicAdd(&hist[u >> 21], 1u);
  }
  __syncthreads();
  if (t < 64){
    unsigned s = 0;
    for (int k2 = 0; k2 < 32; ++k2) s += hist[t*32 + k2];
    unsigned p = s;
    for (int off = 1; off < 64; off <<= 1){ unsigned v = (unsigned)__shfl_up((int)p, off); if (t >= off) p += v; }
    int excl = (int)(p - s);
    if (excl < 1024 && (int)p >= 1024){ scal[0] = t; scal[1] = excl; }
  }
  __syncthreads();
  {
    int g = scal[0];
    if (t < 32){
      unsigned s = hist[g*32 + t];
      unsigned p = s;
      for (int off = 1; off < 32; off <<= 1){ unsigned v = (unsigned)__shfl_up((int)p, off); if (t >= off) p += v; }
      int before = scal[1] + (int)(p - s);
      if (before < 1024 && scal[1] + (int)p >= 1024) scal[2] = g*32 + t;
    }
  }
  __syncthreads();
  unsigned B1 = (unsigned)scal[2];
  unsigned limit = (B1 >= 2047u) ? 0xFFFFFFFFu : ((B1+1u) << 21);
  for (int j = 0; j < 8; ++j){
    int i = t + j*1024;
    unsigned u = dk[i];
    if (u < limit){
      int p = atomicAdd(&scal[3], 1);
      if (p < 2048) win[p] = ((unsigned long long)u << 13) | (unsigned)i;
    }
  }
  __syncthreads();
  int m = scal[3]; if (m > 2048) m = 2048;
  const float far = farval[0];
  for (int e = t; e < m; e += 1024){
    unsigned long long me = win[e];
    int rk = 0;
    for (int j2 = 0; j2 < m; ++j2) rk += (win[j2] < me) ? 1 : 0;
    if (rk < 1024){
      int idx = (int)(me & 0x1FFFull);
      merged[b*2048 + rk] = idx;
      mxyz[base + idx] = make_float4(far, far, far, 0.0f);
    }
  }
}

// ---------------- FPS (bit-exact fp32 chain), 1 block per batch
// R3: ONE barrier per iteration. 3-slot LDS key ring (reset of slot it+1 happens pre-barrier,
// provably race-free). Winner coords fetched by every thread from the float4 masked-coord
// image in global (L1/L2-hot broadcast load) -> no owner-push, no second barrier.
__global__ __launch_bounds__(512) void fps_kernel(const float4* __restrict__ mxyz, int* __restrict__ merged){
  __shared__ unsigned long long slotK[3];
  const int t = threadIdx.x;
  const int b = blockIdx.x;
  const int base = b * N;
  float px[16], py[16], pz[16], md[16];
  #pragma unroll
  for (int j = 0; j < 16; ++j){
    float4 p = mxyz[base + t + j*512];
    px[j] = p.x; py[j] = p.y; pz[j] = p.z; md[j] = 1e10f;
  }
  if (t == 0){
    merged[b*2048 + 1024] = 0;                 // first fps output is index 0
    slotK[0] = 0ull; slotK[1] = 0ull; slotK[2] = 0ull;
  }
  float4 w0 = mxyz[base];                      // masked coords of point 0
  float lx = w0.x, ly = w0.y, lz = w0.z;
  __syncthreads();
  for (int it = 0; it < 1024; ++it){
    float bestv = -1.0f; int bidx = 0;
    #pragma unroll
    for (int j = 0; j < 16; ++j){
      float dx = fsubr(px[j], lx), dy = fsubr(py[j], ly), dz = fsubr(pz[j], lz);
      float d = __fadd_rn(__fadd_rn(__fmul_rn(dx,dx), __fmul_rn(dy,dy)), __fmul_rn(dz,dz));
      float nm = fminf(md[j], d);
      md[j] = nm;
      if (nm > bestv){ bestv = nm; bidx = t + (j<<9); }
    }
    unsigned long long key = ((unsigned long long)__float_as_uint(bestv) << 13)
                           | (unsigned long long)(8191 - bidx);
    #pragma unroll
    for (int off = 32; off; off >>= 1){
      unsigned long long o = __shfl_down(key, off);
      if (o > key) key = o;
    }
    const int s = it % 3;
    const int snext = (s == 2) ? 0 : s + 1;
    if ((t & 63) == 0) atomicMax(&slotK[s], key);
    if (t == 0) slotK[snext] = 0ull;           // last read of snext was before barrier(it-1)
    __syncthreads();
    const unsigned long long k = slotK[s];
    const int idx = 8191 - (int)(k & 0x1FFFull);
    if (t == 0 && it < 1023) merged[b*2048 + 1024 + it + 1] = idx;
    float4 wv = mxyz[base + idx];
    lx = wv.x; ly = wv.y; lz = wv.z;
  }
}

// ---------------- gather outputs: coords + merged-as-float
__global__ void finalize_kernel(const float* __restrict__ xyz, const int* __restrict__ merged,
                                float* __restrict__ out){
  int i = blockIdx.x*256 + threadIdx.x;
  if (i < BATCH*2048){
    int b = i >> 11;
    int idx = merged[i];
    out[12288 + i] = (float)idx;
    const float* p = xyz + (size_t)(b*N + idx)*3;
    out[i*3+0] = p[0]; out[i*3+1] = p[1]; out[i*3+2] = p[2];
  }
}

extern "C" void kernel_launch(void* const* d_in, const int* in_sizes, int n_in,
                              void* d_out, int out_size, void* d_ws, size_t ws_size,
                              hipStream_t stream){
  const float* xyz  = (const float*)d_in[0];
  const float* feat = (const float*)d_in[1];
  const float* w1   = (const float*)d_in[2];
  const float* b1   = (const float*)d_in[3];
  const float* w2   = (const float*)d_in[4];
  const float* b2   = (const float*)d_in[5];
  float* out = (float*)d_out;
  char* ws = (char*)d_ws;
  float*  Q      = (float*) (ws);                  // 16384*128 f32 = 8 MB
  int*    cand   = (int*)   (ws + 8388608);        // 16384*64  i32 = 4 MB
  float*  xs     = (float*) (ws + 12582912);
  float*  ysv    = (float*) (ws + 12648448);
  float*  zsv    = (float*) (ws + 12713984);
  float*  sq     = (float*) (ws + 12779520);
  float*  curv   = (float*) (ws + 12845056);
  float*  fv     = (float*) (ws + 12910592);
  float*  imp    = (float*) (ws + 12976128);
  int*    merged = (int*)   (ws + 13041664);       // 4096 i32
  float*  farval = (float*) (ws + 13058048);       // 1 f32 (+pad)
  float4* mxyz   = (float4*)(ws + 13058112);       // 16384 float4 = 256 KB (16B aligned)

  aux_kernel<<<64, 256, 0, stream>>>(xyz, xs, ysv, zsv, sq, mxyz);
  farval_kernel<<<1, 256, 0, stream>>>(xyz, farval);
  q_kernel<<<1024, 128, 0, stream>>>(xyz, feat, w1, Q);
  knn_kernel<<<512, 512, 0, stream>>>(xs, ysv, zsv, sq, cand);
  score_kernel<<<4096, 256, 0, stream>>>(xyz, feat, Q, b1, w2, b2, cand, curv, fv);
  stats_kernel<<<2, 1024, 0, stream>>>(curv, fv, imp);
  topk_kernel<<<2, 1024, 0, stream>>>(imp, merged, mxyz, farval);
  fps_kernel<<<2, 512, 0, stream>>>(mxyz, merged);
  finalize_kernel<<<16, 256, 0, stream>>>(xyz, merged, out);
}